// Round 13
// baseline (167.353 us; speedup 1.0000x reference)
//
#include <hip/hip_runtime.h>
#include <hip/hip_bf16.h>

// BasicBlock9: B=16, CIN=CP=64, H=W=64, K1=3 (deform), K2=5, EPS=1e-5
// R13: R12 + MERGED phase2/phase3 loop. Phases 2 (deform: LDS-gather+blend)
//   and 3 (conv5: L2 A-stream+MFMA) are independent given the tile; running
//   them interleaved per-kk gives each scheduling window two independent
//   instruction streams (phase-3 MFMAs issue while phase-2 blends wait on
//   LDS). Merged path taken when interior && wave-fast (~94% of blocks);
//   sequential fallback otherwise. Spill tripwire: WRITE_SIZE must stay 8192.

#define HWv 4096
#define EPSv 1e-5f

typedef __attribute__((ext_vector_type(8))) short bf16x8;
typedef __attribute__((ext_vector_type(16))) float f32x16;
typedef __attribute__((ext_vector_type(2))) float f32x2;

__device__ inline ushort f2bf(float f) {
  __hip_bfloat16 h = __float2bfloat16(f);
  return *(ushort*)&h;
}
__device__ inline float bf2f(ushort u) {
  unsigned int t = ((unsigned int)u) << 16;
  union { unsigned int i; float f; } c; c.i = t; return c.f;
}
__device__ inline float bitsf(unsigned int u) {
  union { unsigned int i; float f; } c; c.i = u; return c.f;
}

// ---------------- prep: transpose x + fragment-major weight preps ----------------
__global__ __launch_bounds__(256) void prep_kernel(
    const float* __restrict__ x, const float* __restrict__ w3,
    const float* __restrict__ w2, const float* __restrict__ w1,
    const float* __restrict__ w_off,
    ushort* __restrict__ xT, ushort* __restrict__ w3F,
    ushort* __restrict__ w2F, ushort* __restrict__ w1F,
    ushort* __restrict__ wofF) {
  __shared__ float tile[64][65];
  const int blk = blockIdx.x;
  if (blk < 1024) {
    const int y = blk & 63, b = blk >> 6;
    for (int i = threadIdx.x; i < 4096; i += 256) {
      int ci = i >> 6, xx = i & 63;
      tile[ci][xx] = x[(((size_t)b * 64 + ci) * 64 + y) * 64 + xx];
    }
    __syncthreads();
    for (int i = threadIdx.x; i < 2048; i += 256) {
      int xx = i >> 5, cip = (i & 31) * 2;
      ushort2 v;
      v.x = f2bf(tile[cip][xx]);
      v.y = f2bf(tile[cip + 1][xx]);
      *(ushort2*)&xT[(((size_t)b * 64 + y) * 64 + xx) * 64 + cip] = v;
    }
    return;
  }
  int idx = (blk - 1024) * 256 + threadIdx.x;
  if (idx < 102400) {  // w3F
    int j = idx & 7, lane = (idx >> 3) & 63, ks = (idx >> 9) & 3;
    int half = (idx >> 11) & 1, kk = idx >> 12;
    int ln = lane & 31, kh = lane >> 5;
    int co = half * 32 + ln, ci = ks * 16 + kh * 8 + j;
    w3F[idx] = f2bf(w3[(co * 64 + ci) * 25 + kk]);
    return;
  }
  idx -= 102400;
  if (idx < 36864) {  // w2F
    int j = idx & 7, lane = (idx >> 3) & 63, ks = (idx >> 9) & 3;
    int half = (idx >> 11) & 1, kk = idx >> 12;
    int ln = lane & 31, kh = lane >> 5;
    int co = half * 32 + ln, ci = ks * 16 + kh * 8 + j;
    w2F[idx] = f2bf(w2[(co * 64 + ci) * 9 + kk]);
    return;
  }
  idx -= 36864;
  if (idx < 36864) {  // w1F
    int j = idx & 7, lane = (idx >> 3) & 63, ks = (idx >> 9) & 3;
    int half = (idx >> 11) & 1, kk = idx >> 12;
    int ln = lane & 31, kh = lane >> 5;
    int co = half * 32 + ln, ci = ks * 16 + kh * 8 + j;
    w1F[idx] = f2bf(w1[(co * 64 + ci) * 9 + kk]);
    return;
  }
  idx -= 36864;
  if (idx < 18432) {  // wofF
    int j = idx & 7, lane = (idx >> 3) & 63, ks = (idx >> 9) & 3;
    int kk = idx >> 11;
    int ln = lane & 31, kh = lane >> 5;
    int ci = ks * 16 + kh * 8 + j;
    wofF[idx] = f2bf(ln < 18 ? w_off[(ln * 64 + ci) * 9 + kk] : 0.f);
  }
}

// packed bilinear blend of 4 corner bf16x8 frags -> bf16x8
__device__ __forceinline__ bf16x8 blend4(bf16x8 va, bf16x8 vb, bf16x8 vc, bf16x8 vd,
                                         f32x2 w00v, f32x2 w01v, f32x2 w10v, f32x2 w11v) {
  const unsigned int* ua = (const unsigned int*)&va;
  const unsigned int* ub = (const unsigned int*)&vb;
  const unsigned int* uc = (const unsigned int*)&vc;
  const unsigned int* ud = (const unsigned int*)&vd;
  bf16x8 f;
  ushort2* fo = (ushort2*)&f;
#pragma unroll
  for (int d = 0; d < 4; ++d) {
    f32x2 av = {bitsf(ua[d] << 16), bitsf(ua[d] & 0xFFFF0000u)};
    f32x2 bv = {bitsf(ub[d] << 16), bitsf(ub[d] & 0xFFFF0000u)};
    f32x2 cv = {bitsf(uc[d] << 16), bitsf(uc[d] & 0xFFFF0000u)};
    f32x2 dv = {bitsf(ud[d] << 16), bitsf(ud[d] & 0xFFFF0000u)};
    f32x2 r = w00v * av + w01v * bv + w10v * cv + w11v * dv;
    __hip_bfloat162 h2 = __float22bfloat162_rn(make_float2(r.x, r.y));
    fo[d] = *(ushort2*)&h2;
  }
  return f;
}

// ---------------- fused: offset conv + deform + conv5 -> s1T ----------------
// Grid (32, 16), 256 thr = 4 waves: r = wv>>1 (row), nt = wv&1 (px half).
__global__ __launch_bounds__(256, 2) void fused_kernel(
    const ushort* __restrict__ xT, const ushort* __restrict__ wofF,
    const float* __restrict__ b_off, const ushort* __restrict__ w1F,
    const ushort* __restrict__ w3F,
    const float* __restrict__ g1, const float* __restrict__ b1,
    const float* __restrict__ m1, const float* __restrict__ v1,
    const float* __restrict__ g3, const float* __restrict__ b3,
    const float* __restrict__ m3, const float* __restrict__ v3,
    ushort* __restrict__ s1T) {
  __shared__ __align__(16) uint4 ldsx[6 * 68 * 8];  // 52224 B swizzled tile
  __shared__ float stash[2 * 64 * 18];              // 9216 B offsets
  __shared__ float bn1s[64], bn1b[64], bn3s[64], bn3b[64];  // 1024 B

  const int tid = threadIdx.x;
  const int wv = tid >> 6, lane = tid & 63;
  const int ln = lane & 31, kh = lane >> 5;
  const int r = wv >> 1, nt = wv & 1;
  const int y0 = blockIdx.x * 2, b = blockIdx.y;
  const int y = y0 + r, px = nt * 32 + ln;
  const uint4* xT4 = (const uint4*)xT;
  const bool interior = (y0 >= 2 && y0 <= 60);  // block-uniform

  if (tid < 64) {
    float s = g1[tid] * rsqrtf(v1[tid] + EPSv);
    bn1s[tid] = s; bn1b[tid] = b1[tid] - m1[tid] * s;
    float s3 = g3[tid] * rsqrtf(v3[tid] + EPSv);
    bn3s[tid] = s3; bn3b[tid] = b3[tid] - m3[tid] * s3;
  }
  for (int i = tid; i < 6 * 68 * 8; i += 256) {
    int tr = i / (68 * 8), rem = i % (68 * 8);
    int col = rem >> 3, c = rem & 7;
    int ysrc = min(max(y0 - 2 + tr, 0), 63);
    int xcol = col - 2;
    uint4 v = make_uint4(0, 0, 0, 0);
    if (xcol >= 0 && xcol <= 63)
      v = xT4[((size_t)((b * 64 + ysrc) * 64 + xcol)) * 8 + c];
    ldsx[(tr * 68 + col) * 8 + (c ^ (col & 7))] = v;
  }
  __syncthreads();  // barrier 1

  // ---------- phase 1: offset conv 3x3 ----------
  f32x16 acco;
#pragma unroll
  for (int j = 0; j < 16; ++j) acco[j] = 0.f;
  if (interior) {
#pragma unroll
    for (int kk = 0; kk < 9; ++kk) {
      const int ky = kk / 3, kx = kk % 3;
      const int tr = r + ky + 1;
      const int col = px + kx + 1;
      bf16x8 af[4], bf[4];
#pragma unroll
      for (int ks = 0; ks < 4; ++ks)
        af[ks] = *(const bf16x8*)&wofF[(size_t)((kk * 4 + ks) * 64 + lane) * 8];
#pragma unroll
      for (int ks = 0; ks < 4; ++ks) {
        int c = ks * 2 + kh;
        bf[ks] = *(const bf16x8*)&ldsx[(tr * 68 + col) * 8 + (c ^ (col & 7))];
      }
#pragma unroll
      for (int ks = 0; ks < 4; ++ks)
        acco = __builtin_amdgcn_mfma_f32_32x32x16_bf16(af[ks], bf[ks], acco, 0, 0, 0);
    }
  } else {
#pragma unroll
    for (int kk = 0; kk < 9; ++kk) {
      const int ky = kk / 3, kx = kk % 3;
      const int yy = y - 1 + ky;
      if (yy >= 0 && yy <= 63) {  // wave-uniform
        const int tr = yy - (y0 - 2);
        const int col = px + kx + 1;
#pragma unroll
        for (int ks = 0; ks < 4; ++ks) {
          int c = ks * 2 + kh;
          bf16x8 af = *(const bf16x8*)&wofF[(size_t)((kk * 4 + ks) * 64 + lane) * 8];
          bf16x8 bf = *(const bf16x8*)&ldsx[(tr * 68 + col) * 8 + (c ^ (col & 7))];
          acco = __builtin_amdgcn_mfma_f32_32x32x16_bf16(af, bf, acco, 0, 0, 0);
        }
      }
    }
  }
#pragma unroll
  for (int reg = 0; reg < 16; ++reg) {
    int co = (reg & 3) + 8 * (reg >> 2) + 4 * kh;
    if (co < 18)
      stash[(r * 64 + px) * 18 + co] = acco[reg] + b_off[co];
  }
  __syncthreads();  // barrier 2

  float dyv[9], dxv[9];
#pragma unroll
  for (int kk = 0; kk < 9; ++kk) {
    dyv[kk] = stash[(r * 64 + px) * 18 + 2 * kk];
    dxv[kk] = stash[(r * 64 + px) * 18 + 2 * kk + 1];
  }
  bool fast = true;
#pragma unroll
  for (int kk = 0; kk < 9; ++kk) {
    int iy0 = (int)floorf((float)(y - 1 + kk / 3) + dyv[kk]);
    int iy1 = iy0 + 1;
    bool ok0 = (iy0 < 0) || (iy0 > 63) || (iy0 >= y0 - 2 && iy0 <= y0 + 3);
    bool ok1 = (iy1 < 0) || (iy1 > 63) || (iy1 >= y0 - 2 && iy1 <= y0 + 3);
    fast = fast && ok0 && ok1;
  }
  const bool wavefast = (__ballot(!fast) == 0ull);

  f32x16 accd0, accd1, acc50, acc51;
#pragma unroll
  for (int j = 0; j < 16; ++j) {
    accd0[j] = 0.f; accd1[j] = 0.f; acc50[j] = 0.f; acc51[j] = 0.f;
  }
  const ushort* xb = xT + (size_t)b * 64 * 64 * 64;

  if (interior && wavefast) {
    // ========== merged branch-free phase2+phase3 loop ==========
#pragma unroll
    for (int kk = 0; kk < 25; ++kk) {
      // ---- phase 3 loads (independent stream) ----
      const int ky5 = kk / 5, kx5 = kk % 5;
      const int tr5 = r + ky5, col5 = px + kx5;
      bf16x8 p3a0[4], p3a1[4], p3b[4];
#pragma unroll
      for (int ks = 0; ks < 4; ++ks) {
        p3a0[ks] = *(const bf16x8*)&w3F[(size_t)(((kk * 2 + 0) * 4 + ks) * 64 + lane) * 8];
        p3a1[ks] = *(const bf16x8*)&w3F[(size_t)(((kk * 2 + 1) * 4 + ks) * 64 + lane) * 8];
      }
#pragma unroll
      for (int ks = 0; ks < 4; ++ks) {
        int c = ks * 2 + kh;
        p3b[ks] = *(const bf16x8*)&ldsx[(tr5 * 68 + col5) * 8 + (c ^ (col5 & 7))];
      }
      // ---- phase 2 (deform) for kk < 9, fully unrolled so no branch ----
      if (kk < 9) {
        const int ky = kk / 3, kx = kk % 3;
        float ys = (float)(y - 1 + ky) + dyv[kk];
        float xs = (float)(px - 1 + kx) + dxv[kk];
        float y0f = floorf(ys), x0f = floorf(xs);
        float wy1 = ys - y0f, wx1 = xs - x0f;
        float wy0 = 1.f - wy1, wx0 = 1.f - wx1;
        int iy0 = (int)y0f, ix0 = (int)x0f;
        int iy1 = iy0 + 1, ix1 = ix0 + 1;
        float vy0 = (iy0 >= 0 && iy0 <= 63) ? 1.f : 0.f;
        float vy1 = (iy1 >= 0 && iy1 <= 63) ? 1.f : 0.f;
        float vx0 = (ix0 >= 0 && ix0 <= 63) ? 1.f : 0.f;
        float vx1 = (ix1 >= 0 && ix1 <= 63) ? 1.f : 0.f;
        int x0c = min(max(ix0, 0), 63), x1c = min(max(ix1, 0), 63);
        float w00 = wy0 * wx0 * vy0 * vx0;
        float w01 = wy0 * wx1 * vy0 * vx1;
        float w10 = wy1 * wx0 * vy1 * vx0;
        float w11 = wy1 * wx1 * vy1 * vx1;
        int tr0 = min(max(iy0 - (y0 - 2), 0), 5);
        int tr1 = min(max(iy1 - (y0 - 2), 0), 5);
        int c0 = x0c + 2, c1 = x1c + 2;
        f32x2 w00v = {w00, w00}, w01v = {w01, w01};
        f32x2 w10v = {w10, w10}, w11v = {w11, w11};

        bf16x8 a0[4], a1[4];
#pragma unroll
        for (int ks = 0; ks < 4; ++ks) {
          a0[ks] = *(const bf16x8*)&w1F[(size_t)(((kk * 2 + 0) * 4 + ks) * 64 + lane) * 8];
          a1[ks] = *(const bf16x8*)&w1F[(size_t)(((kk * 2 + 1) * 4 + ks) * 64 + lane) * 8];
        }
#pragma unroll
        for (int ks = 0; ks < 4; ++ks) {
          int c = ks * 2 + kh;
          bf16x8 va = *(const bf16x8*)&ldsx[(tr0 * 68 + c0) * 8 + (c ^ (c0 & 7))];
          bf16x8 vb = *(const bf16x8*)&ldsx[(tr0 * 68 + c1) * 8 + (c ^ (c1 & 7))];
          bf16x8 vc = *(const bf16x8*)&ldsx[(tr1 * 68 + c0) * 8 + (c ^ (c0 & 7))];
          bf16x8 vd = *(const bf16x8*)&ldsx[(tr1 * 68 + c1) * 8 + (c ^ (c1 & 7))];
          bf16x8 f = blend4(va, vb, vc, vd, w00v, w01v, w10v, w11v);
          accd0 = __builtin_amdgcn_mfma_f32_32x32x16_bf16(a0[ks], f, accd0, 0, 0, 0);
          accd1 = __builtin_amdgcn_mfma_f32_32x32x16_bf16(a1[ks], f, accd1, 0, 0, 0);
        }
      }
      // ---- phase 3 MFMAs ----
#pragma unroll
      for (int ks = 0; ks < 4; ++ks) {
        acc50 = __builtin_amdgcn_mfma_f32_32x32x16_bf16(p3a0[ks], p3b[ks], acc50, 0, 0, 0);
        acc51 = __builtin_amdgcn_mfma_f32_32x32x16_bf16(p3a1[ks], p3b[ks], acc51, 0, 0, 0);
      }
    }
  } else {
    // ========== sequential fallback (boundary blocks / slow waves) ==========
#pragma unroll
    for (int kk = 0; kk < 9; ++kk) {
      const int ky = kk / 3, kx = kk % 3;
      float ys = (float)(y - 1 + ky) + dyv[kk];
      float xs = (float)(px - 1 + kx) + dxv[kk];
      float y0f = floorf(ys), x0f = floorf(xs);
      float wy1 = ys - y0f, wx1 = xs - x0f;
      float wy0 = 1.f - wy1, wx0 = 1.f - wx1;
      int iy0 = (int)y0f, ix0 = (int)x0f;
      int iy1 = iy0 + 1, ix1 = ix0 + 1;
      float vy0 = (iy0 >= 0 && iy0 <= 63) ? 1.f : 0.f;
      float vy1 = (iy1 >= 0 && iy1 <= 63) ? 1.f : 0.f;
      float vx0 = (ix0 >= 0 && ix0 <= 63) ? 1.f : 0.f;
      float vx1 = (ix1 >= 0 && ix1 <= 63) ? 1.f : 0.f;
      int x0c = min(max(ix0, 0), 63), x1c = min(max(ix1, 0), 63);
      float w00 = wy0 * wx0 * vy0 * vx0;
      float w01 = wy0 * wx1 * vy0 * vx1;
      float w10 = wy1 * wx0 * vy1 * vx0;
      float w11 = wy1 * wx1 * vy1 * vx1;
      int tr0 = min(max(iy0 - (y0 - 2), 0), 5);
      int tr1 = min(max(iy1 - (y0 - 2), 0), 5);
      int c0 = x0c + 2, c1 = x1c + 2;
      f32x2 w00v = {w00, w00}, w01v = {w01, w01};
      f32x2 w10v = {w10, w10}, w11v = {w11, w11};

      bf16x8 frag[4];
#pragma unroll
      for (int ks = 0; ks < 4; ++ks) {
        int c = ks * 2 + kh;
        bf16x8 va = *(const bf16x8*)&ldsx[(tr0 * 68 + c0) * 8 + (c ^ (c0 & 7))];
        bf16x8 vb = *(const bf16x8*)&ldsx[(tr0 * 68 + c1) * 8 + (c ^ (c1 & 7))];
        bf16x8 vc = *(const bf16x8*)&ldsx[(tr1 * 68 + c0) * 8 + (c ^ (c0 & 7))];
        bf16x8 vd = *(const bf16x8*)&ldsx[(tr1 * 68 + c1) * 8 + (c ^ (c1 & 7))];
        frag[ks] = blend4(va, vb, vc, vd, w00v, w01v, w10v, w11v);
      }
      if (!fast) {
        int y0c = min(max(iy0, 0), 63), y1c = min(max(iy1, 0), 63);
        const ushort* p00 = xb + (y0c * 64 + x0c) * 64 + kh * 8;
        const ushort* p01 = xb + (y0c * 64 + x1c) * 64 + kh * 8;
        const ushort* p10 = xb + (y1c * 64 + x0c) * 64 + kh * 8;
        const ushort* p11 = xb + (y1c * 64 + x1c) * 64 + kh * 8;
#pragma unroll
        for (int ks = 0; ks < 4; ++ks) {
          bf16x8 va = *(const bf16x8*)(p00 + ks * 16);
          bf16x8 vb = *(const bf16x8*)(p01 + ks * 16);
          bf16x8 vc = *(const bf16x8*)(p10 + ks * 16);
          bf16x8 vd = *(const bf16x8*)(p11 + ks * 16);
          frag[ks] = blend4(va, vb, vc, vd, w00v, w01v, w10v, w11v);
        }
      }
#pragma unroll
      for (int ks = 0; ks < 4; ++ks) {
        bf16x8 a0 = *(const bf16x8*)&w1F[(size_t)(((kk * 2 + 0) * 4 + ks) * 64 + lane) * 8];
        bf16x8 a1 = *(const bf16x8*)&w1F[(size_t)(((kk * 2 + 1) * 4 + ks) * 64 + lane) * 8];
        accd0 = __builtin_amdgcn_mfma_f32_32x32x16_bf16(a0, frag[ks], accd0, 0, 0, 0);
        accd1 = __builtin_amdgcn_mfma_f32_32x32x16_bf16(a1, frag[ks], accd1, 0, 0, 0);
      }
    }
#pragma unroll
    for (int kk = 0; kk < 25; ++kk) {
      const int ky = kk / 5, kx = kk % 5;
      const int yy = y - 2 + ky;
      if (yy >= 0 && yy <= 63) {  // wave-uniform
        const int tr = r + ky;
        const int col = px + kx;
#pragma unroll
        for (int ks = 0; ks < 4; ++ks) {
          int c = ks * 2 + kh;
          bf16x8 bf = *(const bf16x8*)&ldsx[(tr * 68 + col) * 8 + (c ^ (col & 7))];
          bf16x8 a0 = *(const bf16x8*)&w3F[(size_t)(((kk * 2 + 0) * 4 + ks) * 64 + lane) * 8];
          bf16x8 a1 = *(const bf16x8*)&w3F[(size_t)(((kk * 2 + 1) * 4 + ks) * 64 + lane) * 8];
          acc50 = __builtin_amdgcn_mfma_f32_32x32x16_bf16(a0, bf, acc50, 0, 0, 0);
          acc51 = __builtin_amdgcn_mfma_f32_32x32x16_bf16(a1, bf, acc51, 0, 0, 0);
        }
      }
    }
  }

  // ---------- epilogue: s1 = relu(bn1(deform)) + relu(bn3(conv5)) ----------
  ushort* op = s1T + ((size_t)((b * 64 + y) * 64 + px)) * 64;
#pragma unroll
  for (int q = 0; q < 4; ++q) {
    int co0 = 8 * q + 4 * kh;
    float vv[4];
#pragma unroll
    for (int rr = 0; rr < 4; ++rr) {
      int co = co0 + rr;
      float vd = accd0[q * 4 + rr] * bn1s[co] + bn1b[co];
      vd = vd > 0.f ? vd : 0.f;
      float v5 = acc50[q * 4 + rr] * bn3s[co] + bn3b[co];
      v5 = v5 > 0.f ? v5 : 0.f;
      vv[rr] = vd + v5;
    }
    ushort4 st;
    st.x = f2bf(vv[0]); st.y = f2bf(vv[1]); st.z = f2bf(vv[2]); st.w = f2bf(vv[3]);
    *(ushort4*)(op + co0) = st;
#pragma unroll
    for (int rr = 0; rr < 4; ++rr) {
      int co = co0 + 32 + rr;
      float vd = accd1[q * 4 + rr] * bn1s[co] + bn1b[co];
      vd = vd > 0.f ? vd : 0.f;
      float v5 = acc51[q * 4 + rr] * bn3s[co] + bn3b[co];
      v5 = v5 > 0.f ? v5 : 0.f;
      vv[rr] = vd + v5;
    }
    st.x = f2bf(vv[0]); st.y = f2bf(vv[1]); st.z = f2bf(vv[2]); st.w = f2bf(vv[3]);
    *(ushort4*)(op + co0 + 32) = st;
  }
}

// ---------------- conv3x3 on s1T + BN2 + residual + ReLU -> out ----------------
__global__ __launch_bounds__(256, 2) void conv3_mfma_kernel(
    const ushort* __restrict__ s1T, const ushort* __restrict__ w2F,
    const float* __restrict__ g2, const float* __restrict__ b2,
    const float* __restrict__ m2, const float* __restrict__ v2,
    const float* __restrict__ x, float* __restrict__ out) {
  __shared__ __align__(16) uint4 Bt[4 * 66 * 8];  // 33.8 KB swizzled
  __shared__ float sc[64], bi[64];
  const int tid = threadIdx.x;
  if (tid < 64) {
    float s = g2[tid] * rsqrtf(v2[tid] + EPSv);
    sc[tid] = s;
    bi[tid] = b2[tid] - m2[tid] * s;
  }
  const int y0 = blockIdx.x * 2, b = blockIdx.y;
  const int w = tid >> 6, lane = tid & 63;
  const int ln = lane & 31, kh = lane >> 5;
  const int mh = w & 1, nt0 = (w >> 1) * 2;
  const uint4* s1T4 = (const uint4*)s1T;

  for (int i = tid; i < 4 * 66 * 8; i += 256) {
    int tr = i / (66 * 8), rem = i % (66 * 8);
    int col = rem >> 3, c = rem & 7;
    int yy = y0 - 1 + tr, xcol = col - 1;
    uint4 v = make_uint4(0, 0, 0, 0);
    if (yy >= 0 && yy <= 63 && xcol >= 0 && xcol <= 63)
      v = s1T4[((size_t)((b * 64 + yy) * 64 + xcol)) * 8 + c];
    Bt[(tr * 66 + col) * 8 + (c ^ (col & 7))] = v;
  }
  __syncthreads();

  f32x16 acc[2];
#pragma unroll
  for (int t = 0; t < 2; ++t)
#pragma unroll
    for (int j = 0; j < 16; ++j) acc[t][j] = 0.f;

#pragma unroll
  for (int ccb = 0; ccb < 4; ++ccb) {
    const int c = ccb * 2 + kh;
#pragma unroll
    for (int kk = 0; kk < 9; ++kk) {
      const int ky = kk / 3, kx = kk % 3;
      bf16x8 af = *(const bf16x8*)&w2F[(size_t)(((kk * 2 + mh) * 4 + ccb) * 64 + lane) * 8];
#pragma unroll
      for (int t = 0; t < 2; ++t) {
        int p = (nt0 + t) * 32 + ln;
        int ry = p >> 6, px = p & 63;
        int col = px + kx;
        bf16x8 bfr = *(const bf16x8*)&Bt[((ry + ky) * 66 + col) * 8 + (c ^ (col & 7))];
        acc[t] = __builtin_amdgcn_mfma_f32_32x32x16_bf16(af, bfr, acc[t], 0, 0, 0);
      }
    }
  }
#pragma unroll
  for (int t = 0; t < 2; ++t) {
    int p = (nt0 + t) * 32 + ln;
    int y = y0 + (p >> 6), px = p & 63;
#pragma unroll
    for (int reg = 0; reg < 16; ++reg) {
      int co = (reg & 3) + 8 * (reg >> 2) + 4 * kh + mh * 32;
      size_t o = (((size_t)b * 64 + co) * 64 + y) * 64 + px;
      float v = acc[t][reg] * sc[co] + bi[co] + x[o];
      out[o] = v > 0.f ? v : 0.f;
    }
  }
}

extern "C" void kernel_launch(void* const* d_in, const int* in_sizes, int n_in,
                              void* d_out, int out_size, void* d_ws, size_t ws_size,
                              hipStream_t stream) {
  const float* x     = (const float*)d_in[0];
  const float* w_off = (const float*)d_in[1];
  const float* b_off = (const float*)d_in[2];
  const float* w1    = (const float*)d_in[3];
  const float* g1    = (const float*)d_in[4];
  const float* b1    = (const float*)d_in[5];
  const float* m1    = (const float*)d_in[6];
  const float* v1    = (const float*)d_in[7];
  const float* w3    = (const float*)d_in[8];
  const float* g3    = (const float*)d_in[9];
  const float* b3    = (const float*)d_in[10];
  const float* m3    = (const float*)d_in[11];
  const float* v3    = (const float*)d_in[12];
  const float* w2    = (const float*)d_in[13];
  const float* g2    = (const float*)d_in[14];
  const float* b2    = (const float*)d_in[15];
  const float* m2    = (const float*)d_in[16];
  const float* v2    = (const float*)d_in[17];
  float* out = (float*)d_out;

  ushort* xT   = (ushort*)d_ws;                  // 16*64*4096 bf16 = 8.39 MB
  ushort* s1T  = xT + (size_t)16 * 64 * HWv;     // 8.39 MB
  ushort* w3F  = s1T + (size_t)16 * 64 * HWv;    // 102400
  ushort* w2F  = w3F + 102400;                   // 36864
  ushort* w1F  = w2F + 36864;                    // 36864
  ushort* wofF = w1F + 36864;                    // 18432

  prep_kernel<<<dim3(1024 + 760), dim3(256), 0, stream>>>(x, w3, w2, w1, w_off,
                                                          xT, w3F, w2F, w1F, wofF);
  fused_kernel<<<dim3(32, 16), dim3(256), 0, stream>>>(xT, wofF, b_off, w1F, w3F,
                                                       g1, b1, m1, v1, g3, b3, m3, v3,
                                                       s1T);
  conv3_mfma_kernel<<<dim3(32, 16), dim3(256), 0, stream>>>(s1T, w2F, g2, b2, m2, v2,
                                                            x, out);
}

// Round 14
// 161.099 us; speedup vs baseline: 1.0388x; 1.0388x over previous
//
#include <hip/hip_runtime.h>
#include <hip/hip_bf16.h>

// BasicBlock9: B=16, CIN=CP=64, H=W=64, K1=3 (deform), K2=5, EPS=1e-5
// R14: fused = R12-exact (best measured: 50.5us). conv3 -> 1-row blocks:
//   grid (64,16)=1024 blocks, 3-row tile (25.3KB) -> 4 blocks/CU = 4
//   waves/SIMD (2x latency hiding vs 2-row blocks; R10's failure mode --
//   duplicated blend -- doesn't exist here). One acc chain per wave
//   (mh,nt quadrants), loads grouped per-kk.

#define HWv 4096
#define EPSv 1e-5f

typedef __attribute__((ext_vector_type(8))) short bf16x8;
typedef __attribute__((ext_vector_type(16))) float f32x16;
typedef __attribute__((ext_vector_type(2))) float f32x2;

__device__ inline ushort f2bf(float f) {
  __hip_bfloat16 h = __float2bfloat16(f);
  return *(ushort*)&h;
}
__device__ inline float bf2f(ushort u) {
  unsigned int t = ((unsigned int)u) << 16;
  union { unsigned int i; float f; } c; c.i = t; return c.f;
}
__device__ inline float bitsf(unsigned int u) {
  union { unsigned int i; float f; } c; c.i = u; return c.f;
}

// ---------------- prep: transpose x + fragment-major weight preps ----------------
__global__ __launch_bounds__(256) void prep_kernel(
    const float* __restrict__ x, const float* __restrict__ w3,
    const float* __restrict__ w2, const float* __restrict__ w1,
    const float* __restrict__ w_off,
    ushort* __restrict__ xT, ushort* __restrict__ w3F,
    ushort* __restrict__ w2F, ushort* __restrict__ w1F,
    ushort* __restrict__ wofF) {
  __shared__ float tile[64][65];
  const int blk = blockIdx.x;
  if (blk < 1024) {
    const int y = blk & 63, b = blk >> 6;
    for (int i = threadIdx.x; i < 4096; i += 256) {
      int ci = i >> 6, xx = i & 63;
      tile[ci][xx] = x[(((size_t)b * 64 + ci) * 64 + y) * 64 + xx];
    }
    __syncthreads();
    for (int i = threadIdx.x; i < 2048; i += 256) {
      int xx = i >> 5, cip = (i & 31) * 2;
      ushort2 v;
      v.x = f2bf(tile[cip][xx]);
      v.y = f2bf(tile[cip + 1][xx]);
      *(ushort2*)&xT[(((size_t)b * 64 + y) * 64 + xx) * 64 + cip] = v;
    }
    return;
  }
  int idx = (blk - 1024) * 256 + threadIdx.x;
  if (idx < 102400) {  // w3F
    int j = idx & 7, lane = (idx >> 3) & 63, ks = (idx >> 9) & 3;
    int half = (idx >> 11) & 1, kk = idx >> 12;
    int ln = lane & 31, kh = lane >> 5;
    int co = half * 32 + ln, ci = ks * 16 + kh * 8 + j;
    w3F[idx] = f2bf(w3[(co * 64 + ci) * 25 + kk]);
    return;
  }
  idx -= 102400;
  if (idx < 36864) {  // w2F
    int j = idx & 7, lane = (idx >> 3) & 63, ks = (idx >> 9) & 3;
    int half = (idx >> 11) & 1, kk = idx >> 12;
    int ln = lane & 31, kh = lane >> 5;
    int co = half * 32 + ln, ci = ks * 16 + kh * 8 + j;
    w2F[idx] = f2bf(w2[(co * 64 + ci) * 9 + kk]);
    return;
  }
  idx -= 36864;
  if (idx < 36864) {  // w1F
    int j = idx & 7, lane = (idx >> 3) & 63, ks = (idx >> 9) & 3;
    int half = (idx >> 11) & 1, kk = idx >> 12;
    int ln = lane & 31, kh = lane >> 5;
    int co = half * 32 + ln, ci = ks * 16 + kh * 8 + j;
    w1F[idx] = f2bf(w1[(co * 64 + ci) * 9 + kk]);
    return;
  }
  idx -= 36864;
  if (idx < 18432) {  // wofF
    int j = idx & 7, lane = (idx >> 3) & 63, ks = (idx >> 9) & 3;
    int kk = idx >> 11;
    int ln = lane & 31, kh = lane >> 5;
    int ci = ks * 16 + kh * 8 + j;
    wofF[idx] = f2bf(ln < 18 ? w_off[(ln * 64 + ci) * 9 + kk] : 0.f);
  }
}

// packed bilinear blend of 4 corner bf16x8 frags -> bf16x8
__device__ __forceinline__ bf16x8 blend4(bf16x8 va, bf16x8 vb, bf16x8 vc, bf16x8 vd,
                                         f32x2 w00v, f32x2 w01v, f32x2 w10v, f32x2 w11v) {
  const unsigned int* ua = (const unsigned int*)&va;
  const unsigned int* ub = (const unsigned int*)&vb;
  const unsigned int* uc = (const unsigned int*)&vc;
  const unsigned int* ud = (const unsigned int*)&vd;
  bf16x8 f;
  ushort2* fo = (ushort2*)&f;
#pragma unroll
  for (int d = 0; d < 4; ++d) {
    f32x2 av = {bitsf(ua[d] << 16), bitsf(ua[d] & 0xFFFF0000u)};
    f32x2 bv = {bitsf(ub[d] << 16), bitsf(ub[d] & 0xFFFF0000u)};
    f32x2 cv = {bitsf(uc[d] << 16), bitsf(uc[d] & 0xFFFF0000u)};
    f32x2 dv = {bitsf(ud[d] << 16), bitsf(ud[d] & 0xFFFF0000u)};
    f32x2 r = w00v * av + w01v * bv + w10v * cv + w11v * dv;
    __hip_bfloat162 h2 = __float22bfloat162_rn(make_float2(r.x, r.y));
    fo[d] = *(ushort2*)&h2;
  }
  return f;
}

// ---------------- fused: offset conv + deform + conv5 -> s1T (R12-exact) ----------------
// Grid (32, 16), 256 thr = 4 waves: r = wv>>1 (row), nt = wv&1 (px half).
__global__ __launch_bounds__(256, 2) void fused_kernel(
    const ushort* __restrict__ xT, const ushort* __restrict__ wofF,
    const float* __restrict__ b_off, const ushort* __restrict__ w1F,
    const ushort* __restrict__ w3F,
    const float* __restrict__ g1, const float* __restrict__ b1,
    const float* __restrict__ m1, const float* __restrict__ v1,
    const float* __restrict__ g3, const float* __restrict__ b3,
    const float* __restrict__ m3, const float* __restrict__ v3,
    ushort* __restrict__ s1T) {
  __shared__ __align__(16) uint4 ldsx[6 * 68 * 8];  // 52224 B swizzled tile
  __shared__ float stash[2 * 64 * 18];              // 9216 B offsets
  __shared__ float bn1s[64], bn1b[64], bn3s[64], bn3b[64];  // 1024 B

  const int tid = threadIdx.x;
  const int wv = tid >> 6, lane = tid & 63;
  const int ln = lane & 31, kh = lane >> 5;
  const int r = wv >> 1, nt = wv & 1;
  const int y0 = blockIdx.x * 2, b = blockIdx.y;
  const int y = y0 + r, px = nt * 32 + ln;
  const uint4* xT4 = (const uint4*)xT;
  const bool interior = (y0 >= 2 && y0 <= 60);  // block-uniform

  if (tid < 64) {
    float s = g1[tid] * rsqrtf(v1[tid] + EPSv);
    bn1s[tid] = s; bn1b[tid] = b1[tid] - m1[tid] * s;
    float s3 = g3[tid] * rsqrtf(v3[tid] + EPSv);
    bn3s[tid] = s3; bn3b[tid] = b3[tid] - m3[tid] * s3;
  }
  for (int i = tid; i < 6 * 68 * 8; i += 256) {
    int tr = i / (68 * 8), rem = i % (68 * 8);
    int col = rem >> 3, c = rem & 7;
    int ysrc = min(max(y0 - 2 + tr, 0), 63);
    int xcol = col - 2;
    uint4 v = make_uint4(0, 0, 0, 0);
    if (xcol >= 0 && xcol <= 63)
      v = xT4[((size_t)((b * 64 + ysrc) * 64 + xcol)) * 8 + c];
    ldsx[(tr * 68 + col) * 8 + (c ^ (col & 7))] = v;
  }
  __syncthreads();  // barrier 1

  // ---------- phase 1: offset conv 3x3 ----------
  f32x16 acco;
#pragma unroll
  for (int j = 0; j < 16; ++j) acco[j] = 0.f;
  if (interior) {
#pragma unroll
    for (int kk = 0; kk < 9; ++kk) {
      const int ky = kk / 3, kx = kk % 3;
      const int tr = r + ky + 1;
      const int col = px + kx + 1;
      bf16x8 af[4], bf[4];
#pragma unroll
      for (int ks = 0; ks < 4; ++ks)
        af[ks] = *(const bf16x8*)&wofF[(size_t)((kk * 4 + ks) * 64 + lane) * 8];
#pragma unroll
      for (int ks = 0; ks < 4; ++ks) {
        int c = ks * 2 + kh;
        bf[ks] = *(const bf16x8*)&ldsx[(tr * 68 + col) * 8 + (c ^ (col & 7))];
      }
#pragma unroll
      for (int ks = 0; ks < 4; ++ks)
        acco = __builtin_amdgcn_mfma_f32_32x32x16_bf16(af[ks], bf[ks], acco, 0, 0, 0);
    }
  } else {
#pragma unroll
    for (int kk = 0; kk < 9; ++kk) {
      const int ky = kk / 3, kx = kk % 3;
      const int yy = y - 1 + ky;
      if (yy >= 0 && yy <= 63) {  // wave-uniform
        const int tr = yy - (y0 - 2);
        const int col = px + kx + 1;
#pragma unroll
        for (int ks = 0; ks < 4; ++ks) {
          int c = ks * 2 + kh;
          bf16x8 af = *(const bf16x8*)&wofF[(size_t)((kk * 4 + ks) * 64 + lane) * 8];
          bf16x8 bf = *(const bf16x8*)&ldsx[(tr * 68 + col) * 8 + (c ^ (col & 7))];
          acco = __builtin_amdgcn_mfma_f32_32x32x16_bf16(af, bf, acco, 0, 0, 0);
        }
      }
    }
  }
#pragma unroll
  for (int reg = 0; reg < 16; ++reg) {
    int co = (reg & 3) + 8 * (reg >> 2) + 4 * kh;
    if (co < 18)
      stash[(r * 64 + px) * 18 + co] = acco[reg] + b_off[co];
  }
  __syncthreads();  // barrier 2

  float dyv[9], dxv[9];
#pragma unroll
  for (int kk = 0; kk < 9; ++kk) {
    dyv[kk] = stash[(r * 64 + px) * 18 + 2 * kk];
    dxv[kk] = stash[(r * 64 + px) * 18 + 2 * kk + 1];
  }
  bool fast = true;
#pragma unroll
  for (int kk = 0; kk < 9; ++kk) {
    int iy0 = (int)floorf((float)(y - 1 + kk / 3) + dyv[kk]);
    int iy1 = iy0 + 1;
    bool ok0 = (iy0 < 0) || (iy0 > 63) || (iy0 >= y0 - 2 && iy0 <= y0 + 3);
    bool ok1 = (iy1 < 0) || (iy1 > 63) || (iy1 >= y0 - 2 && iy1 <= y0 + 3);
    fast = fast && ok0 && ok1;
  }

  // ---------- phase 2: deformable conv 3x3 ----------
  f32x16 accd0, accd1;
#pragma unroll
  for (int j = 0; j < 16; ++j) { accd0[j] = 0.f; accd1[j] = 0.f; }
  const ushort* xb = xT + (size_t)b * 64 * 64 * 64;

  if (__ballot(!fast) == 0ull) {
    // -------- branch-free fast loop (whole wave in-tile) --------
#pragma unroll
    for (int kk = 0; kk < 9; ++kk) {
      const int ky = kk / 3, kx = kk % 3;
      float ys = (float)(y - 1 + ky) + dyv[kk];
      float xs = (float)(px - 1 + kx) + dxv[kk];
      float y0f = floorf(ys), x0f = floorf(xs);
      float wy1 = ys - y0f, wx1 = xs - x0f;
      float wy0 = 1.f - wy1, wx0 = 1.f - wx1;
      int iy0 = (int)y0f, ix0 = (int)x0f;
      int iy1 = iy0 + 1, ix1 = ix0 + 1;
      float vy0 = (iy0 >= 0 && iy0 <= 63) ? 1.f : 0.f;
      float vy1 = (iy1 >= 0 && iy1 <= 63) ? 1.f : 0.f;
      float vx0 = (ix0 >= 0 && ix0 <= 63) ? 1.f : 0.f;
      float vx1 = (ix1 >= 0 && ix1 <= 63) ? 1.f : 0.f;
      int x0c = min(max(ix0, 0), 63), x1c = min(max(ix1, 0), 63);
      float w00 = wy0 * wx0 * vy0 * vx0;
      float w01 = wy0 * wx1 * vy0 * vx1;
      float w10 = wy1 * wx0 * vy1 * vx0;
      float w11 = wy1 * wx1 * vy1 * vx1;
      int tr0 = min(max(iy0 - (y0 - 2), 0), 5);
      int tr1 = min(max(iy1 - (y0 - 2), 0), 5);
      int c0 = x0c + 2, c1 = x1c + 2;
      f32x2 w00v = {w00, w00}, w01v = {w01, w01};
      f32x2 w10v = {w10, w10}, w11v = {w11, w11};

      bf16x8 a0[4], a1[4], va[4], vb[4], vc[4], vd[4];
#pragma unroll
      for (int ks = 0; ks < 4; ++ks) {
        a0[ks] = *(const bf16x8*)&w1F[(size_t)(((kk * 2 + 0) * 4 + ks) * 64 + lane) * 8];
        a1[ks] = *(const bf16x8*)&w1F[(size_t)(((kk * 2 + 1) * 4 + ks) * 64 + lane) * 8];
      }
#pragma unroll
      for (int ks = 0; ks < 4; ++ks) {
        int c = ks * 2 + kh;
        va[ks] = *(const bf16x8*)&ldsx[(tr0 * 68 + c0) * 8 + (c ^ (c0 & 7))];
        vb[ks] = *(const bf16x8*)&ldsx[(tr0 * 68 + c1) * 8 + (c ^ (c1 & 7))];
        vc[ks] = *(const bf16x8*)&ldsx[(tr1 * 68 + c0) * 8 + (c ^ (c0 & 7))];
        vd[ks] = *(const bf16x8*)&ldsx[(tr1 * 68 + c1) * 8 + (c ^ (c1 & 7))];
      }
#pragma unroll
      for (int ks = 0; ks < 4; ++ks) {
        bf16x8 f = blend4(va[ks], vb[ks], vc[ks], vd[ks], w00v, w01v, w10v, w11v);
        accd0 = __builtin_amdgcn_mfma_f32_32x32x16_bf16(a0[ks], f, accd0, 0, 0, 0);
        accd1 = __builtin_amdgcn_mfma_f32_32x32x16_bf16(a1[ks], f, accd1, 0, 0, 0);
      }
    }
  } else {
    // -------- mixed loop (rare: some lane needs global gather) --------
#pragma unroll
    for (int kk = 0; kk < 9; ++kk) {
      const int ky = kk / 3, kx = kk % 3;
      float ys = (float)(y - 1 + ky) + dyv[kk];
      float xs = (float)(px - 1 + kx) + dxv[kk];
      float y0f = floorf(ys), x0f = floorf(xs);
      float wy1 = ys - y0f, wx1 = xs - x0f;
      float wy0 = 1.f - wy1, wx0 = 1.f - wx1;
      int iy0 = (int)y0f, ix0 = (int)x0f;
      int iy1 = iy0 + 1, ix1 = ix0 + 1;
      float vy0 = (iy0 >= 0 && iy0 <= 63) ? 1.f : 0.f;
      float vy1 = (iy1 >= 0 && iy1 <= 63) ? 1.f : 0.f;
      float vx0 = (ix0 >= 0 && ix0 <= 63) ? 1.f : 0.f;
      float vx1 = (ix1 >= 0 && ix1 <= 63) ? 1.f : 0.f;
      int x0c = min(max(ix0, 0), 63), x1c = min(max(ix1, 0), 63);
      float w00 = wy0 * wx0 * vy0 * vx0;
      float w01 = wy0 * wx1 * vy0 * vx1;
      float w10 = wy1 * wx0 * vy1 * vx0;
      float w11 = wy1 * wx1 * vy1 * vx1;
      int tr0 = min(max(iy0 - (y0 - 2), 0), 5);
      int tr1 = min(max(iy1 - (y0 - 2), 0), 5);
      int c0 = x0c + 2, c1 = x1c + 2;
      f32x2 w00v = {w00, w00}, w01v = {w01, w01};
      f32x2 w10v = {w10, w10}, w11v = {w11, w11};

      bf16x8 frag[4];
#pragma unroll
      for (int ks = 0; ks < 4; ++ks) {
        int c = ks * 2 + kh;
        bf16x8 va = *(const bf16x8*)&ldsx[(tr0 * 68 + c0) * 8 + (c ^ (c0 & 7))];
        bf16x8 vb = *(const bf16x8*)&ldsx[(tr0 * 68 + c1) * 8 + (c ^ (c1 & 7))];
        bf16x8 vc = *(const bf16x8*)&ldsx[(tr1 * 68 + c0) * 8 + (c ^ (c0 & 7))];
        bf16x8 vd = *(const bf16x8*)&ldsx[(tr1 * 68 + c1) * 8 + (c ^ (c1 & 7))];
        frag[ks] = blend4(va, vb, vc, vd, w00v, w01v, w10v, w11v);
      }
      if (!fast) {
        int y0c = min(max(iy0, 0), 63), y1c = min(max(iy1, 0), 63);
        const ushort* p00 = xb + (y0c * 64 + x0c) * 64 + kh * 8;
        const ushort* p01 = xb + (y0c * 64 + x1c) * 64 + kh * 8;
        const ushort* p10 = xb + (y1c * 64 + x0c) * 64 + kh * 8;
        const ushort* p11 = xb + (y1c * 64 + x1c) * 64 + kh * 8;
#pragma unroll
        for (int ks = 0; ks < 4; ++ks) {
          bf16x8 va = *(const bf16x8*)(p00 + ks * 16);
          bf16x8 vb = *(const bf16x8*)(p01 + ks * 16);
          bf16x8 vc = *(const bf16x8*)(p10 + ks * 16);
          bf16x8 vd = *(const bf16x8*)(p11 + ks * 16);
          frag[ks] = blend4(va, vb, vc, vd, w00v, w01v, w10v, w11v);
        }
      }
#pragma unroll
      for (int ks = 0; ks < 4; ++ks) {
        bf16x8 a0 = *(const bf16x8*)&w1F[(size_t)(((kk * 2 + 0) * 4 + ks) * 64 + lane) * 8];
        bf16x8 a1 = *(const bf16x8*)&w1F[(size_t)(((kk * 2 + 1) * 4 + ks) * 64 + lane) * 8];
        accd0 = __builtin_amdgcn_mfma_f32_32x32x16_bf16(a0, frag[ks], accd0, 0, 0, 0);
        accd1 = __builtin_amdgcn_mfma_f32_32x32x16_bf16(a1, frag[ks], accd1, 0, 0, 0);
      }
    }
  }

  // ---------- phase 3: conv 5x5 ----------
  f32x16 acc50, acc51;
#pragma unroll
  for (int j = 0; j < 16; ++j) { acc50[j] = 0.f; acc51[j] = 0.f; }
  if (interior) {
#pragma unroll
    for (int kk = 0; kk < 25; ++kk) {
      const int ky = kk / 5, kx = kk % 5;
      const int tr = r + ky;
      const int col = px + kx;
      bf16x8 a0[4], a1[4], bfv[4];
#pragma unroll
      for (int ks = 0; ks < 4; ++ks) {
        a0[ks] = *(const bf16x8*)&w3F[(size_t)(((kk * 2 + 0) * 4 + ks) * 64 + lane) * 8];
        a1[ks] = *(const bf16x8*)&w3F[(size_t)(((kk * 2 + 1) * 4 + ks) * 64 + lane) * 8];
      }
#pragma unroll
      for (int ks = 0; ks < 4; ++ks) {
        int c = ks * 2 + kh;
        bfv[ks] = *(const bf16x8*)&ldsx[(tr * 68 + col) * 8 + (c ^ (col & 7))];
      }
#pragma unroll
      for (int ks = 0; ks < 4; ++ks) {
        acc50 = __builtin_amdgcn_mfma_f32_32x32x16_bf16(a0[ks], bfv[ks], acc50, 0, 0, 0);
        acc51 = __builtin_amdgcn_mfma_f32_32x32x16_bf16(a1[ks], bfv[ks], acc51, 0, 0, 0);
      }
    }
  } else {
#pragma unroll
    for (int kk = 0; kk < 25; ++kk) {
      const int ky = kk / 5, kx = kk % 5;
      const int yy = y - 2 + ky;
      if (yy >= 0 && yy <= 63) {  // wave-uniform
        const int tr = r + ky;
        const int col = px + kx;
#pragma unroll
        for (int ks = 0; ks < 4; ++ks) {
          int c = ks * 2 + kh;
          bf16x8 bf = *(const bf16x8*)&ldsx[(tr * 68 + col) * 8 + (c ^ (col & 7))];
          bf16x8 a0 = *(const bf16x8*)&w3F[(size_t)(((kk * 2 + 0) * 4 + ks) * 64 + lane) * 8];
          bf16x8 a1 = *(const bf16x8*)&w3F[(size_t)(((kk * 2 + 1) * 4 + ks) * 64 + lane) * 8];
          acc50 = __builtin_amdgcn_mfma_f32_32x32x16_bf16(a0, bf, acc50, 0, 0, 0);
          acc51 = __builtin_amdgcn_mfma_f32_32x32x16_bf16(a1, bf, acc51, 0, 0, 0);
        }
      }
    }
  }

  // ---------- epilogue ----------
  ushort* op = s1T + ((size_t)((b * 64 + y) * 64 + px)) * 64;
#pragma unroll
  for (int q = 0; q < 4; ++q) {
    int co0 = 8 * q + 4 * kh;
    float vv[4];
#pragma unroll
    for (int rr = 0; rr < 4; ++rr) {
      int co = co0 + rr;
      float vd = accd0[q * 4 + rr] * bn1s[co] + bn1b[co];
      vd = vd > 0.f ? vd : 0.f;
      float v5 = acc50[q * 4 + rr] * bn3s[co] + bn3b[co];
      v5 = v5 > 0.f ? v5 : 0.f;
      vv[rr] = vd + v5;
    }
    ushort4 st;
    st.x = f2bf(vv[0]); st.y = f2bf(vv[1]); st.z = f2bf(vv[2]); st.w = f2bf(vv[3]);
    *(ushort4*)(op + co0) = st;
#pragma unroll
    for (int rr = 0; rr < 4; ++rr) {
      int co = co0 + 32 + rr;
      float vd = accd1[q * 4 + rr] * bn1s[co] + bn1b[co];
      vd = vd > 0.f ? vd : 0.f;
      float v5 = acc51[q * 4 + rr] * bn3s[co] + bn3b[co];
      v5 = v5 > 0.f ? v5 : 0.f;
      vv[rr] = vd + v5;
    }
    st.x = f2bf(vv[0]); st.y = f2bf(vv[1]); st.z = f2bf(vv[2]); st.w = f2bf(vv[3]);
    *(ushort4*)(op + co0 + 32) = st;
  }
}

// ---------------- conv3x3 on s1T + BN2 + residual + ReLU -> out ----------------
// R14: 1-row blocks. Grid (64,16)=1024 blocks, 256 thr = 4 waves (mh, nt).
// 3-row tile (25344 B) -> 4 blocks/CU = 4 waves/SIMD. One acc chain/wave.
__global__ __launch_bounds__(256, 2) void conv3_mfma_kernel(
    const ushort* __restrict__ s1T, const ushort* __restrict__ w2F,
    const float* __restrict__ g2, const float* __restrict__ b2,
    const float* __restrict__ m2, const float* __restrict__ v2,
    const float* __restrict__ x, float* __restrict__ out) {
  __shared__ __align__(16) uint4 Bt[3 * 66 * 8];  // 25344 B swizzled
  __shared__ float sc[64], bi[64];
  const int tid = threadIdx.x;
  if (tid < 64) {
    float s = g2[tid] * rsqrtf(v2[tid] + EPSv);
    sc[tid] = s;
    bi[tid] = b2[tid] - m2[tid] * s;
  }
  const int y = blockIdx.x, b = blockIdx.y;
  const int wv = tid >> 6, lane = tid & 63;
  const int ln = lane & 31, kh = lane >> 5;
  const int mh = wv & 1, nt = wv >> 1;
  const int px = nt * 32 + ln;
  const uint4* s1T4 = (const uint4*)s1T;

  // stage rows y-1..y+1 (OOB rows zero), cols 0..65 = x cols -1..64 (OOB zero)
  for (int i = tid; i < 3 * 66 * 8; i += 256) {
    int tr = i / (66 * 8), rem = i % (66 * 8);
    int col = rem >> 3, c = rem & 7;
    int yy = y - 1 + tr, xcol = col - 1;
    uint4 v = make_uint4(0, 0, 0, 0);
    if (yy >= 0 && yy <= 63 && xcol >= 0 && xcol <= 63)
      v = s1T4[((size_t)((b * 64 + yy) * 64 + xcol)) * 8 + c];
    Bt[(tr * 66 + col) * 8 + (c ^ (col & 7))] = v;
  }
  __syncthreads();

  f32x16 acc;
#pragma unroll
  for (int j = 0; j < 16; ++j) acc[j] = 0.f;

#pragma unroll
  for (int kk = 0; kk < 9; ++kk) {
    const int ky = kk / 3, kx = kk % 3;
    const int col = px + kx;
    bf16x8 af[4], bfr[4];
#pragma unroll
    for (int ccb = 0; ccb < 4; ++ccb)
      af[ccb] = *(const bf16x8*)&w2F[(size_t)(((kk * 2 + mh) * 4 + ccb) * 64 + lane) * 8];
#pragma unroll
    for (int ccb = 0; ccb < 4; ++ccb) {
      int c = ccb * 2 + kh;
      bfr[ccb] = *(const bf16x8*)&Bt[(ky * 66 + col) * 8 + (c ^ (col & 7))];
    }
#pragma unroll
    for (int ccb = 0; ccb < 4; ++ccb)
      acc = __builtin_amdgcn_mfma_f32_32x32x16_bf16(af[ccb], bfr[ccb], acc, 0, 0, 0);
  }
#pragma unroll
  for (int reg = 0; reg < 16; ++reg) {
    int co = (reg & 3) + 8 * (reg >> 2) + 4 * kh + mh * 32;
    size_t o = (((size_t)b * 64 + co) * 64 + y) * 64 + px;
    float v = acc[reg] * sc[co] + bi[co] + x[o];
    out[o] = v > 0.f ? v : 0.f;
  }
}

extern "C" void kernel_launch(void* const* d_in, const int* in_sizes, int n_in,
                              void* d_out, int out_size, void* d_ws, size_t ws_size,
                              hipStream_t stream) {
  const float* x     = (const float*)d_in[0];
  const float* w_off = (const float*)d_in[1];
  const float* b_off = (const float*)d_in[2];
  const float* w1    = (const float*)d_in[3];
  const float* g1    = (const float*)d_in[4];
  const float* b1    = (const float*)d_in[5];
  const float* m1    = (const float*)d_in[6];
  const float* v1    = (const float*)d_in[7];
  const float* w3    = (const float*)d_in[8];
  const float* g3    = (const float*)d_in[9];
  const float* b3    = (const float*)d_in[10];
  const float* m3    = (const float*)d_in[11];
  const float* v3    = (const float*)d_in[12];
  const float* w2    = (const float*)d_in[13];
  const float* g2    = (const float*)d_in[14];
  const float* b2    = (const float*)d_in[15];
  const float* m2    = (const float*)d_in[16];
  const float* v2    = (const float*)d_in[17];
  float* out = (float*)d_out;

  ushort* xT   = (ushort*)d_ws;                  // 16*64*4096 bf16 = 8.39 MB
  ushort* s1T  = xT + (size_t)16 * 64 * HWv;     // 8.39 MB
  ushort* w3F  = s1T + (size_t)16 * 64 * HWv;    // 102400
  ushort* w2F  = w3F + 102400;                   // 36864
  ushort* w1F  = w2F + 36864;                    // 36864
  ushort* wofF = w1F + 36864;                    // 18432

  prep_kernel<<<dim3(1024 + 760), dim3(256), 0, stream>>>(x, w3, w2, w1, w_off,
                                                          xT, w3F, w2F, w1F, wofF);
  fused_kernel<<<dim3(32, 16), dim3(256), 0, stream>>>(xT, wofF, b_off, w1F, w3F,
                                                       g1, b1, m1, v1, g3, b3, m3, v3,
                                                       s1T);
  conv3_mfma_kernel<<<dim3(64, 16), dim3(256), 0, stream>>>(s1T, w2F, g2, b2, m2, v2,
                                                            x, out);
}